// Round 7
// baseline (694.592 us; speedup 1.0000x reference)
//
#include <hip/hip_runtime.h>
#include <hip/hip_fp16.h>
#include <math.h>

#define SEQ 343
#define CCH 192
#define NWIN 128
#define NHEAD 6
#define TOK (NWIN * SEQ)  // 43904

typedef __bf16 bf16x8 __attribute__((ext_vector_type(8)));
typedef float f32x4 __attribute__((ext_vector_type(4)));
typedef float f32x16 __attribute__((ext_vector_type(16)));
typedef unsigned short ushort8 __attribute__((ext_vector_type(8)));
typedef _Float16 half8 __attribute__((ext_vector_type(8)));
typedef _Float16 hv2 __attribute__((ext_vector_type(2)));

__device__ __forceinline__ unsigned short f2bf(float f) {
    unsigned u = __float_as_uint(f);
    u += 0x7FFF + ((u >> 16) & 1);
    return (unsigned short)(u >> 16);
}

// tanh-approx gelu (matches jax.nn.gelu approximate=True), via fast exp
__device__ __forceinline__ float gelu_tanh(float x) {
    const float k0 = 0.7978845608028654f;
    const float k1 = 0.044715f;
    float y = k0 * (x + k1 * x * x * x);
    float t = 1.0f - 2.0f / (__expf(2.0f * y) + 1.0f);
    return 0.5f * x * (1.0f + t);
}

// async global->LDS, 16B per lane
__device__ __forceinline__ void gld16(void* l, const void* g) {
    __builtin_amdgcn_global_load_lds((const __attribute__((address_space(1))) unsigned int*)g,
                                     (__attribute__((address_space(3))) unsigned int*)l, 16, 0, 0);
}

__device__ __forceinline__ hv2 pkrtz(float a, float b) {
    return __builtin_bit_cast(hv2, __builtin_amdgcn_cvt_pkrtz(a, b));
}
__device__ __forceinline__ hv2 u2h2(unsigned u) { return __builtin_bit_cast(hv2, u); }
__device__ __forceinline__ unsigned h22u(hv2 h) { return __builtin_bit_cast(unsigned, h); }

// ---------------- shift (+3 src) + window partition: x(28,56,28,192) -> xw(128,343,192) fp32
__global__ __launch_bounds__(256) void k_shift_part(const float* __restrict__ x,
                                                    float* __restrict__ xw) {
    int idx = blockIdx.x * 256 + threadIdx.x;  // float4 index
    if (idx >= TOK * 48) return;
    int c4 = idx % 48;
    int tok = idx / 48;
    int t = tok % SEQ;
    int wn = tok / SEQ;
    int tw = t % 7, th = (t / 7) % 7, td = t / 49;
    int ww = wn & 3, wh = (wn >> 2) & 7, wd = wn >> 5;
    int sd = (wd * 7 + td + 3) % 28;
    int sh = (wh * 7 + th + 3) % 56;
    int sw = (ww * 7 + tw + 3) % 28;
    const float4* src = (const float4*)(x + (size_t)((sd * 56 + sh) * 28 + sw) * CCH);
    ((float4*)xw)[idx] = src[c4];
}

// ---------------- LayerNorm fp32 -> bf16 (GEMM A operand)
__global__ __launch_bounds__(256) void k_ln_bf(const float* __restrict__ in,
                                               const float* __restrict__ w,
                                               const float* __restrict__ b,
                                               unsigned short* __restrict__ out, int rows) {
    int row = blockIdx.x * 4 + (threadIdx.x >> 6);
    int lane = threadIdx.x & 63;
    if (row >= rows) return;
    const float* p = in + (size_t)row * CCH;
    float v0 = p[lane], v1 = p[lane + 64], v2 = p[lane + 128];
    float s = v0 + v1 + v2;
#pragma unroll
    for (int off = 32; off > 0; off >>= 1) s += __shfl_xor(s, off);
    float mu = s * (1.0f / 192.0f);
    float d0 = v0 - mu, d1 = v1 - mu, d2 = v2 - mu;
    float vv = d0 * d0 + d1 * d1 + d2 * d2;
#pragma unroll
    for (int off = 32; off > 0; off >>= 1) vv += __shfl_xor(vv, off);
    float rs = rsqrtf(vv * (1.0f / 192.0f) + 1e-5f);
    unsigned short* q = out + (size_t)row * CCH;
    q[lane] = f2bf(d0 * rs * w[lane] + b[lane]);
    q[lane + 64] = f2bf(d1 * rs * w[lane + 64] + b[lane + 64]);
    q[lane + 128] = f2bf(d2 * rs * w[lane + 128] + b[lane + 128]);
}

// ---------------- final LN + window reverse + roll(+3) -> d_out (fp32)
__global__ __launch_bounds__(256) void k_ln_out(const float* __restrict__ xw,
                                                const float* __restrict__ w,
                                                const float* __restrict__ b,
                                                float* __restrict__ out) {
    int row = blockIdx.x * 4 + (threadIdx.x >> 6);
    int lane = threadIdx.x & 63;
    if (row >= TOK) return;
    int d = row / 1568;
    int hh = (row / 28) % 56;
    int wv = row % 28;
    int sd = (d + 25) % 28, sh = (hh + 53) % 56, sw = (wv + 25) % 28;
    int wn = (sd / 7) * 32 + (sh / 7) * 4 + (sw / 7);
    int t = (sd % 7) * 49 + (sh % 7) * 7 + (sw % 7);
    const float* p = xw + ((size_t)wn * SEQ + t) * CCH;
    float v0 = p[lane], v1 = p[lane + 64], v2 = p[lane + 128];
    float s = v0 + v1 + v2;
#pragma unroll
    for (int off = 32; off > 0; off >>= 1) s += __shfl_xor(s, off);
    float mu = s * (1.0f / 192.0f);
    float d0 = v0 - mu, d1 = v1 - mu, d2 = v2 - mu;
    float vv = d0 * d0 + d1 * d1 + d2 * d2;
#pragma unroll
    for (int off = 32; off > 0; off >>= 1) vv += __shfl_xor(vv, off);
    float rs = rsqrtf(vv * (1.0f / 192.0f) + 1e-5f);
    float* q = out + (size_t)row * CCH;
    q[lane] = d0 * rs * w[lane] + b[lane];
    q[lane + 64] = d1 * rs * w[lane + 64] + b[lane + 64];
    q[lane + 128] = d2 * rs * w[lane + 128] + b[lane + 128];
}

// ---------------- weight prep: fp32 [K][N] -> bf16 transposed [N][K], both layers
__global__ __launch_bounds__(256) void k_wprep(const float* __restrict__ qkv_w,
                                               const float* __restrict__ out_w,
                                               const float* __restrict__ ff1_w,
                                               const float* __restrict__ ff2_w,
                                               unsigned short* __restrict__ wt) {
    int idx = blockIdx.x * 256 + threadIdx.x;
    if (idx >= 1179648) return;
    int l = idx / 589824;
    int r = idx - l * 589824;
    const float* src;
    int Kd, Nd, off;
    if (r < 110592)      { src = qkv_w + (size_t)l * 110592; Kd = 192; Nd = 576;  off = r; }
    else if (r < 147456) { src = out_w + (size_t)l * 36864;  Kd = 192; Nd = 192;  off = r - 110592; }
    else if (r < 442368) { src = ff1_w + (size_t)l * 294912; Kd = 192; Nd = 1536; off = r - 147456; }
    else                 { src = ff2_w + (size_t)l * 147456; Kd = 768; Nd = 192;  off = r - 442368; }
    int n = off / Kd, k = off - n * Kd;
    wt[idx] = f2bf(src[(size_t)k * Nd + n]);
}

// ---------------- combined mask+bias (log2 domain), u64-packed by k4-group:
// cb4[cl][h][k4 (88)][q (352)] = 4 f16 for k = 4*k4 .. +3
__global__ void k_cbgen3(const float* __restrict__ mask, const float* __restrict__ rpb,
                         uint2* __restrict__ cb4) {
    int q = threadIdx.x;   // 0..351
    int k4 = blockIdx.x;   // 0..87
    int h = blockIdx.y;    // 0..5
    int cl = blockIdx.z;   // 0..7
    int wn = ((cl & 4) ? 96 : 0) + ((cl & 2) ? 28 : 0) + ((cl & 1) ? 3 : 0);
    const float LOG2E = 1.4426950408889634f;
    int qd = q / 49, qh = (q / 7) % 7, qw = q % 7;
    unsigned v[4];
#pragma unroll
    for (int t = 0; t < 4; ++t) {
        int k = 4 * k4 + t;
        float val = -14000.0f;
        if (k < SEQ && q < SEQ) {
            float mk = mask[((size_t)wn * SEQ + k) * SEQ + q];  // mask symmetric in !=0
            if (mk == 0.0f) {
                int kd = k / 49, kh = (k / 7) % 7, kw = k % 7;
                int rel = (qd - kd + 6) * 169 + (qh - kh + 6) * 13 + (qw - kw + 6);
                val = rpb[(size_t)rel * NHEAD + h] * LOG2E;
            }
        }
        v[t] = __half_as_ushort(__float2half_rn(val));
    }
    uint2 pk = {v[0] | (v[1] << 16), v[2] | (v[3] << 16)};
    cb4[((size_t)(cl * NHEAD + h) * 88 + k4) * 352 + q] = pk;
}

// ---------------- 32x32x16 MFMA GEMM, global_load_lds staging, swizzled LDS (linear dest,
// pre-swizzled global source; read applies same XOR). BM=128, BK=64 (rows = 128B exactly).
// MODE 0 (qkv): BN=192, grid.x in {0,1,2} -> Q(scaled)/K -> outH[row][384]; V -> outV transposed.
// MODE 1: BN=64, outF[row*N+col] += acc + bias  (residual fp32)
// MODE 2 (GLU): BN=64, Wt rows [n0,n0+64)=u, [768+n0,...)=g; outB = bf16(u * gelu(g))
template <int MODE>
__global__ __launch_bounds__(256) void k_gemm32(const unsigned short* __restrict__ A,
                                                const unsigned short* __restrict__ Wt,
                                                const float* __restrict__ bias,
                                                float* __restrict__ outF,
                                                unsigned short* __restrict__ outB,
                                                _Float16* __restrict__ outH,
                                                _Float16* __restrict__ outV,
                                                int N, int K) {
    constexpr int BN = (MODE == 0) ? 192 : 64;
    constexpr int NF = (MODE == 0) ? 3 : 1;          // n-frags (of 32) per wave
    constexpr int WNC = NF * 32;                     // wave n-extent
    constexpr int BROWS = (MODE == 0) ? 192 : ((MODE == 2) ? 128 : 64);
    constexpr int BCH = (BROWS * 128) / 4096;        // B DMA chunks
    __shared__ char AsB[16384];
    __shared__ char BsB[BROWS * 128];
    const int tid = threadIdx.x;
    const int n0 = blockIdx.x * BN;
    const size_t m0 = (size_t)blockIdx.y * 128;
    const int lane = tid & 63, wid = tid >> 6;
    const int wm = wid >> 1, wn = wid & 1;
    const int ln31 = lane & 31, hi16 = (lane >> 5) * 16;
    const int xorv = (ln31 & 7) << 4;
    const size_t ldb = (size_t)K * 2;  // row pitch (bytes) of both A and Wt

    f32x16 acc[2][NF];
    f32x16 accG[2];
#pragma unroll
    for (int mi = 0; mi < 2; ++mi) {
#pragma unroll
        for (int nj = 0; nj < NF; ++nj) acc[mi][nj] = (f32x16)(0.f);
        accG[mi] = (f32x16)(0.f);
    }

    for (int kb = 0; kb < K; kb += 64) {
        // ---- stage A (16 KB) + B via DMA, global source pre-swizzled
#pragma unroll
        for (int i = 0; i < 4; ++i) {
            int s = i * 4096 + tid * 16;
            int r = s >> 7;
            int cb = (s & 127) ^ ((r & 7) << 4);
            gld16(AsB + s, (const char*)A + (m0 + r) * ldb + (size_t)kb * 2 + cb);
        }
#pragma unroll
        for (int i = 0; i < BCH; ++i) {
            int s = i * 4096 + tid * 16;
            int r = s >> 7;
            int cb = (s & 127) ^ ((r & 7) << 4);
            int grow = n0 + r + ((MODE == 2 && r >= 64) ? 704 : 0);
            gld16(BsB + s, (const char*)Wt + (size_t)grow * ldb + (size_t)kb * 2 + cb);
        }
        __syncthreads();
        // ---- compute 4 k-steps of 16
#pragma unroll
        for (int ks = 0; ks < 4; ++ks) {
            const int ccb = (ks * 32 + hi16) ^ xorv;
            bf16x8 a0 = *(const bf16x8*)(AsB + (wm * 64 + ln31) * 128 + ccb);
            bf16x8 a1 = *(const bf16x8*)(AsB + (wm * 64 + 32 + ln31) * 128 + ccb);
            if (MODE == 2) {
                bf16x8 bu = *(const bf16x8*)(BsB + (wn * 32 + ln31) * 128 + ccb);
                bf16x8 bg = *(const bf16x8*)(BsB + (64 + wn * 32 + ln31) * 128 + ccb);
                acc[0][0] = __builtin_amdgcn_mfma_f32_32x32x16_bf16(a0, bu, acc[0][0], 0, 0, 0);
                acc[1][0] = __builtin_amdgcn_mfma_f32_32x32x16_bf16(a1, bu, acc[1][0], 0, 0, 0);
                accG[0] = __builtin_amdgcn_mfma_f32_32x32x16_bf16(a0, bg, accG[0], 0, 0, 0);
                accG[1] = __builtin_amdgcn_mfma_f32_32x32x16_bf16(a1, bg, accG[1], 0, 0, 0);
            } else {
#pragma unroll
                for (int nj = 0; nj < NF; ++nj) {
                    bf16x8 b = *(const bf16x8*)(BsB + (wn * WNC + nj * 32 + ln31) * 128 + ccb);
                    acc[0][nj] = __builtin_amdgcn_mfma_f32_32x32x16_bf16(a0, b, acc[0][nj], 0, 0, 0);
                    acc[1][nj] = __builtin_amdgcn_mfma_f32_32x32x16_bf16(a1, b, acc[1][nj], 0, 0, 0);
                }
            }
        }
        __syncthreads();
    }

    // ---- epilogue. C/D: col=lane&31, row=(reg&3)+8*(reg>>2)+4*(lane>>5)
    const float S2LOG = 0.17677669529663687f * 1.4426950408889634f;  // scale*log2e
    const int rbase = (int)m0 + wm * 64 + ((lane >> 5) << 2);
    const int cbase = n0 + wn * WNC + ln31;
#pragma unroll
    for (int mi = 0; mi < 2; ++mi) {
#pragma unroll
        for (int nj = 0; nj < NF; ++nj) {
            const int gc = cbase + nj * 32;
            const float bb = bias[gc];
            const float bgv = (MODE == 2) ? bias[768 + gc] : 0.f;
#pragma unroll
            for (int reg = 0; reg < 16; ++reg) {
                const int row = rbase + mi * 32 + (reg & 3) + ((reg >> 2) << 3);
                float v = acc[mi][nj][reg] + bb;
                if (MODE == 1) {
                    outF[(size_t)row * N + gc] += v;
                } else if (MODE == 0) {
                    if (n0 < 384) {
                        outH[(size_t)row * 384 + gc] = (_Float16)(n0 == 0 ? v * S2LOG : v);
                    } else {
                        int d = gc - 384, hh = d >> 5, dd = d & 31;
                        int wnn = row / 343, qq = row - wnn * 343;
                        outV[(((size_t)wnn * NHEAD + hh) * 32 + dd) * 344 + qq] = (_Float16)v;
                    }
                } else {
                    float g = accG[mi][reg] + bgv;
                    outB[(size_t)row * 768 + gc] = f2bf(v * gelu_tanh(g));
                }
            }
        }
    }
}

// ---------------- attn4: block per (head, window), 4 waves, packed-f16 softmax,
// bpermute P-redistribution (no P LDS), XOR-chunk-swizzled K/V LDS. 44KB LDS -> 3 blocks/CU.
__global__ __launch_bounds__(256) void k_attn4(const _Float16* __restrict__ qk,  // [TOK][384]
                                               const _Float16* __restrict__ vt,  // [128][6][32][344]
                                               const uint2* __restrict__ cb4,
                                               unsigned short* __restrict__ o) {
    __shared__ _Float16 Ks[352 * 32];  // 22528 B, chunk-swizzled: slot = c ^ ((row>>2)&3)
    __shared__ _Float16 Vt[32 * 352];  // 22528 B, chunk-swizzled: slot = ch ^ ((d>>2)&3)
    const int h = blockIdx.x;
    const int wn = blockIdx.y;
    const int tid = threadIdx.x;
    // stage K (352 rows x 32 ch; rows>=343 are garbage-but-finite, masked by cb4)
    const _Float16* kbase = qk + (size_t)wn * SEQ * 384 + 192 + h * 32;
    for (int j = tid; j < 1408; j += 256) {
        int s = j >> 2, c = j & 3;
        int slot = c ^ ((s >> 2) & 3);
        *(half8*)&Ks[s * 32 + slot * 8] = *(const half8*)&kbase[(size_t)s * 384 + c * 8];
    }
    // stage V^T (32 d x 352 k; k>=343 garbage-but-finite, P there is exactly 0)
    const _Float16* vbase = vt + ((size_t)wn * NHEAD + h) * 32 * 344;
    for (int j = tid; j < 1408; j += 256) {
        int d = j / 44, ch = j % 44;
        int slot = ch ^ ((d >> 2) & 3);
        *(half8*)&Vt[d * 352 + slot * 8] = *(const half8*)&vbase[(size_t)d * 344 + ch * 8];
    }
    __syncthreads();
    const int wid = tid >> 6, lane = tid & 63;
    const int qloc = lane & 15, g = lane >> 4;
    const int xq = (qloc >> 2) & 3;
    const int slotK = (g ^ xq) * 8;
    const int iA = (qloc | ((g & 1) << 5)) * 4;  // bpermute byte index of source lane
    const int iB = iA + 64;
    const bool ghi = g >= 2;
    int cls = (((wn >> 5) == 3) ? 4 : 0) | ((((wn >> 2) & 7) == 7) ? 2 : 0) | (((wn & 3) == 3) ? 1 : 0);
    const uint2* cbb = cb4 + (size_t)(cls * NHEAD + h) * 88 * 352;
    for (int qt = wid; qt < 22; qt += 4) {
        const int q0 = qt * 16;
        const int qrow = q0 + qloc;
        half8 qf = *(const half8*)&qk[((size_t)wn * SEQ + qrow) * 384 + h * 32 + g * 8];
        unsigned spk[22][2];
        hv2 mpk = {(_Float16)(-60000.0f), (_Float16)(-60000.0f)};
        __builtin_amdgcn_s_setprio(1);
#pragma unroll
        for (int kt = 0; kt < 22; ++kt) {
            half8 kf = *(const half8*)&Ks[(kt * 16 + qloc) * 32 + slotK];
            f32x4 st = __builtin_amdgcn_mfma_f32_16x16x32_f16(kf, qf, (f32x4){0.f, 0.f, 0.f, 0.f}, 0, 0, 0);
            uint2 cv = cbb[(size_t)(kt * 4 + g) * 352 + qrow];
            hv2 s01 = pkrtz(st[0], st[1]) + u2h2(cv.x);
            hv2 s23 = pkrtz(st[2], st[3]) + u2h2(cv.y);
            mpk = __builtin_elementwise_max(mpk, __builtin_elementwise_max(s01, s23));
            spk[kt][0] = h22u(s01);
            spk[kt][1] = h22u(s23);
        }
        __builtin_amdgcn_s_setprio(0);
        float mf = fmaxf((float)mpk[0], (float)mpk[1]);
        mf = fmaxf(mf, __shfl_xor(mf, 16));
        mf = fmaxf(mf, __shfl_xor(mf, 32));
        float l = 0.f;
#pragma unroll
        for (int kt = 0; kt < 22; ++kt) {
            hv2 s01 = u2h2(spk[kt][0]);
            hv2 s23 = u2h2(spk[kt][1]);
            float e0 = exp2f((float)s01[0] - mf), e1 = exp2f((float)s01[1] - mf);
            float e2 = exp2f((float)s23[0] - mf), e3 = exp2f((float)s23[1] - mf);
            l += (e0 + e1) + (e2 + e3);
            spk[kt][0] = h22u(pkrtz(e0, e1));
            spk[kt][1] = h22u(pkrtz(e2, e3));
        }
        l += __shfl_xor(l, 16);
        l += __shfl_xor(l, 32);
        f32x4 acc0 = {0.f, 0.f, 0.f, 0.f}, acc1 = {0.f, 0.f, 0.f, 0.f};
        __builtin_amdgcn_s_setprio(1);
#pragma unroll
        for (int ch = 0; ch < 11; ++ch) {
            unsigned a0 = __builtin_amdgcn_ds_bpermute(iA, spk[2 * ch][0]);
            unsigned a1 = __builtin_amdgcn_ds_bpermute(iA, spk[2 * ch][1]);
            unsigned a2 = __builtin_amdgcn_ds_bpermute(iB, spk[2 * ch][0]);
            unsigned a3 = __builtin_amdgcn_ds_bpermute(iB, spk[2 * ch][1]);
            unsigned b0 = __builtin_amdgcn_ds_bpermute(iA, spk[2 * ch + 1][0]);
            unsigned b1 = __builtin_amdgcn_ds_bpermute(iA, spk[2 * ch + 1][1]);
            unsigned b2 = __builtin_amdgcn_ds_bpermute(iB, spk[2 * ch + 1][0]);
            unsigned b3 = __builtin_amdgcn_ds_bpermute(iB, spk[2 * ch + 1][1]);
            uint4 pfu = {ghi ? b0 : a0, ghi ? b1 : a1, ghi ? b2 : a2, ghi ? b3 : a3};
            half8 pf = __builtin_bit_cast(half8, pfu);
            const int slotV = ((ch * 4 + g) ^ xq) * 8;
            half8 v0 = *(const half8*)&Vt[qloc * 352 + slotV];
            half8 v1 = *(const half8*)&Vt[(qloc + 16) * 352 + slotV];
            acc0 = __builtin_amdgcn_mfma_f32_16x16x32_f16(v0, pf, acc0, 0, 0, 0);
            acc1 = __builtin_amdgcn_mfma_f32_16x16x32_f16(v1, pf, acc1, 0, 0, 0);
        }
        __builtin_amdgcn_s_setprio(0);
        if (qrow < SEQ) {
            float inv = 1.0f / l;
            unsigned short* orow = o + ((size_t)wn * SEQ + qrow) * CCH + h * 32;
            ushort4 w0 = {f2bf(acc0[0] * inv), f2bf(acc0[1] * inv),
                          f2bf(acc0[2] * inv), f2bf(acc0[3] * inv)};
            ushort4 w1 = {f2bf(acc1[0] * inv), f2bf(acc1[1] * inv),
                          f2bf(acc1[2] * inv), f2bf(acc1[3] * inv)};
            *(ushort4*)&orow[g * 4] = w0;
            *(ushort4*)&orow[16 + g * 4] = w1;
        }
    }
}

extern "C" void kernel_launch(void* const* d_in, const int* in_sizes, int n_in,
                              void* d_out, int out_size, void* d_ws, size_t ws_size,
                              hipStream_t stream) {
    const float* x     = (const float*)d_in[0];
    const float* mask  = (const float*)d_in[1];
    const float* ln1_w = (const float*)d_in[3];
    const float* ln1_b = (const float*)d_in[4];
    const float* qkv_w = (const float*)d_in[5];
    const float* qkv_b = (const float*)d_in[6];
    const float* out_w = (const float*)d_in[7];
    const float* out_b = (const float*)d_in[8];
    const float* ln2_w = (const float*)d_in[9];
    const float* ln2_b = (const float*)d_in[10];
    const float* ff1_w = (const float*)d_in[11];
    const float* ff1_b = (const float*)d_in[12];
    const float* ff2_w = (const float*)d_in[13];
    const float* ff2_b = (const float*)d_in[14];
    const float* rpb   = (const float*)d_in[15];
    const float* lnf_w = (const float*)d_in[16];
    const float* lnf_b = (const float*)d_in[17];

    char* wsp = (char*)d_ws;
    float* xw = (float*)wsp;                          wsp += (size_t)TOK * 192 * 4;
    unsigned short* hdnb = (unsigned short*)wsp;      wsp += (size_t)TOK * 192 * 2;
    _Float16* qkh = (_Float16*)wsp;                   wsp += (size_t)TOK * 384 * 2;
    _Float16* vth = (_Float16*)wsp;                   wsp += (size_t)NWIN * NHEAD * 32 * 344 * 2;
    unsigned short* glub = (unsigned short*)wsp;      wsp += (size_t)TOK * 768 * 2;
    unsigned short* wt = (unsigned short*)wsp;        wsp += (size_t)1179648 * 2;
    uint2* cb4 = (uint2*)wsp;                         // 48*88*352*8 = 11.9 MB
    float* out = (float*)d_out;

    k_shift_part<<<8232, 256, 0, stream>>>(x, xw);
    k_wprep<<<4608, 256, 0, stream>>>(qkv_w, out_w, ff1_w, ff2_w, wt);
    for (int l = 0; l < 2; ++l) {
        unsigned short* wbase = wt + (size_t)l * 589824;
        k_cbgen3<<<dim3(88, NHEAD, 8), 352, 0, stream>>>(mask, rpb + (size_t)l * 2197 * NHEAD, cb4);
        k_ln_bf<<<10976, 256, 0, stream>>>(xw, ln1_w + l * 192, ln1_b + l * 192, hdnb, TOK);
        k_gemm32<0><<<dim3(3, 343), 256, 0, stream>>>(hdnb, wbase, qkv_b + l * 576,
                                                      nullptr, nullptr, qkh, vth, 576, 192);
        k_attn4<<<dim3(NHEAD, NWIN), 256, 0, stream>>>(qkh, vth, cb4, hdnb);
        k_gemm32<1><<<dim3(3, 343), 256, 0, stream>>>(hdnb, wbase + 110592, out_b + l * 192,
                                                      xw, nullptr, nullptr, nullptr, 192, 192);
        k_ln_bf<<<10976, 256, 0, stream>>>(xw, ln2_w + l * 192, ln2_b + l * 192, hdnb, TOK);
        k_gemm32<2><<<dim3(12, 343), 256, 0, stream>>>(hdnb, wbase + 147456, ff1_b + l * 1536,
                                                       nullptr, glub, nullptr, nullptr, 768, 192);
        k_gemm32<1><<<dim3(3, 343), 256, 0, stream>>>(glub, wbase + 442368, ff2_b + l * 192,
                                                      xw, nullptr, nullptr, nullptr, 192, 768);
    }
    k_ln_out<<<10976, 256, 0, stream>>>(xw, lnf_w, lnf_b, out);
}

// Round 8
// 620.538 us; speedup vs baseline: 1.1193x; 1.1193x over previous
//
#include <hip/hip_runtime.h>
#include <hip/hip_fp16.h>
#include <math.h>

#define SEQ 343
#define CCH 192
#define NWIN 128
#define NHEAD 6
#define TOK (NWIN * SEQ)  // 43904

typedef __bf16 bf16x8 __attribute__((ext_vector_type(8)));
typedef float f32x4 __attribute__((ext_vector_type(4)));
typedef float f32x16 __attribute__((ext_vector_type(16)));
typedef unsigned short ushort8 __attribute__((ext_vector_type(8)));
typedef _Float16 half8 __attribute__((ext_vector_type(8)));
typedef _Float16 half4 __attribute__((ext_vector_type(4)));
typedef _Float16 hv2 __attribute__((ext_vector_type(2)));

__device__ __forceinline__ unsigned short f2bf(float f) {
    unsigned u = __float_as_uint(f);
    u += 0x7FFF + ((u >> 16) & 1);
    return (unsigned short)(u >> 16);
}

// tanh-approx gelu (matches jax.nn.gelu approximate=True), via fast exp
__device__ __forceinline__ float gelu_tanh(float x) {
    const float k0 = 0.7978845608028654f;
    const float k1 = 0.044715f;
    float y = k0 * (x + k1 * x * x * x);
    float t = 1.0f - 2.0f / (__expf(2.0f * y) + 1.0f);
    return 0.5f * x * (1.0f + t);
}

// async global->LDS, 16B per lane
__device__ __forceinline__ void gld16(void* l, const void* g) {
    __builtin_amdgcn_global_load_lds((const __attribute__((address_space(1))) unsigned int*)g,
                                     (__attribute__((address_space(3))) unsigned int*)l, 16, 0, 0);
}

__device__ __forceinline__ hv2 pkrtz(float a, float b) {
    return __builtin_bit_cast(hv2, __builtin_amdgcn_cvt_pkrtz(a, b));
}
__device__ __forceinline__ hv2 u2h2(unsigned u) { return __builtin_bit_cast(hv2, u); }
__device__ __forceinline__ unsigned h22u(hv2 h) { return __builtin_bit_cast(unsigned, h); }

// ---------------- shift (+3 src) + window partition: x(28,56,28,192) -> xw(128,343,192) fp32
__global__ __launch_bounds__(256) void k_shift_part(const float* __restrict__ x,
                                                    float* __restrict__ xw) {
    int idx = blockIdx.x * 256 + threadIdx.x;  // float4 index
    if (idx >= TOK * 48) return;
    int c4 = idx % 48;
    int tok = idx / 48;
    int t = tok % SEQ;
    int wn = tok / SEQ;
    int tw = t % 7, th = (t / 7) % 7, td = t / 49;
    int ww = wn & 3, wh = (wn >> 2) & 7, wd = wn >> 5;
    int sd = (wd * 7 + td + 3) % 28;
    int sh = (wh * 7 + th + 3) % 56;
    int sw = (ww * 7 + tw + 3) % 28;
    const float4* src = (const float4*)(x + (size_t)((sd * 56 + sh) * 28 + sw) * CCH);
    ((float4*)xw)[idx] = src[c4];
}

// ---------------- LayerNorm fp32 -> bf16 (GEMM A operand)
__global__ __launch_bounds__(256) void k_ln_bf(const float* __restrict__ in,
                                               const float* __restrict__ w,
                                               const float* __restrict__ b,
                                               unsigned short* __restrict__ out, int rows) {
    int row = blockIdx.x * 4 + (threadIdx.x >> 6);
    int lane = threadIdx.x & 63;
    if (row >= rows) return;
    const float* p = in + (size_t)row * CCH;
    float v0 = p[lane], v1 = p[lane + 64], v2 = p[lane + 128];
    float s = v0 + v1 + v2;
#pragma unroll
    for (int off = 32; off > 0; off >>= 1) s += __shfl_xor(s, off);
    float mu = s * (1.0f / 192.0f);
    float d0 = v0 - mu, d1 = v1 - mu, d2 = v2 - mu;
    float vv = d0 * d0 + d1 * d1 + d2 * d2;
#pragma unroll
    for (int off = 32; off > 0; off >>= 1) vv += __shfl_xor(vv, off);
    float rs = rsqrtf(vv * (1.0f / 192.0f) + 1e-5f);
    unsigned short* q = out + (size_t)row * CCH;
    q[lane] = f2bf(d0 * rs * w[lane] + b[lane]);
    q[lane + 64] = f2bf(d1 * rs * w[lane + 64] + b[lane + 64]);
    q[lane + 128] = f2bf(d2 * rs * w[lane + 128] + b[lane + 128]);
}

// ---------------- final LN + window reverse + roll(+3) -> d_out (fp32)
__global__ __launch_bounds__(256) void k_ln_out(const float* __restrict__ xw,
                                                const float* __restrict__ w,
                                                const float* __restrict__ b,
                                                float* __restrict__ out) {
    int row = blockIdx.x * 4 + (threadIdx.x >> 6);
    int lane = threadIdx.x & 63;
    if (row >= TOK) return;
    int d = row / 1568;
    int hh = (row / 28) % 56;
    int wv = row % 28;
    int sd = (d + 25) % 28, sh = (hh + 53) % 56, sw = (wv + 25) % 28;
    int wn = (sd / 7) * 32 + (sh / 7) * 4 + (sw / 7);
    int t = (sd % 7) * 49 + (sh % 7) * 7 + (sw % 7);
    const float* p = xw + ((size_t)wn * SEQ + t) * CCH;
    float v0 = p[lane], v1 = p[lane + 64], v2 = p[lane + 128];
    float s = v0 + v1 + v2;
#pragma unroll
    for (int off = 32; off > 0; off >>= 1) s += __shfl_xor(s, off);
    float mu = s * (1.0f / 192.0f);
    float d0 = v0 - mu, d1 = v1 - mu, d2 = v2 - mu;
    float vv = d0 * d0 + d1 * d1 + d2 * d2;
#pragma unroll
    for (int off = 32; off > 0; off >>= 1) vv += __shfl_xor(vv, off);
    float rs = rsqrtf(vv * (1.0f / 192.0f) + 1e-5f);
    float* q = out + (size_t)row * CCH;
    q[lane] = d0 * rs * w[lane] + b[lane];
    q[lane + 64] = d1 * rs * w[lane + 64] + b[lane + 64];
    q[lane + 128] = d2 * rs * w[lane + 128] + b[lane + 128];
}

// ---------------- weight prep: fp32 [K][N] -> bf16 transposed [N][K], both layers
__global__ __launch_bounds__(256) void k_wprep(const float* __restrict__ qkv_w,
                                               const float* __restrict__ out_w,
                                               const float* __restrict__ ff1_w,
                                               const float* __restrict__ ff2_w,
                                               unsigned short* __restrict__ wt) {
    int idx = blockIdx.x * 256 + threadIdx.x;
    if (idx >= 1179648) return;
    int l = idx / 589824;
    int r = idx - l * 589824;
    const float* src;
    int Kd, Nd, off;
    if (r < 110592)      { src = qkv_w + (size_t)l * 110592; Kd = 192; Nd = 576;  off = r; }
    else if (r < 147456) { src = out_w + (size_t)l * 36864;  Kd = 192; Nd = 192;  off = r - 110592; }
    else if (r < 442368) { src = ff1_w + (size_t)l * 294912; Kd = 192; Nd = 1536; off = r - 147456; }
    else                 { src = ff2_w + (size_t)l * 147456; Kd = 768; Nd = 192;  off = r - 442368; }
    int n = off / Kd, k = off - n * Kd;
    wt[idx] = f2bf(src[(size_t)k * Nd + n]);
}

// ---------------- combined mask+bias (log2 domain), u64-packed by k4-group:
// cb4[cl][h][k4 (88)][q (352)] = 4 f16 for k = 4*k4 .. +3
__global__ void k_cbgen3(const float* __restrict__ mask, const float* __restrict__ rpb,
                         uint2* __restrict__ cb4) {
    int q = threadIdx.x;   // 0..351
    int k4 = blockIdx.x;   // 0..87
    int h = blockIdx.y;    // 0..5
    int cl = blockIdx.z;   // 0..7
    int wn = ((cl & 4) ? 96 : 0) + ((cl & 2) ? 28 : 0) + ((cl & 1) ? 3 : 0);
    const float LOG2E = 1.4426950408889634f;
    int qd = q / 49, qh = (q / 7) % 7, qw = q % 7;
    unsigned v[4];
#pragma unroll
    for (int t = 0; t < 4; ++t) {
        int k = 4 * k4 + t;
        float val = -14000.0f;
        if (k < SEQ && q < SEQ) {
            float mk = mask[((size_t)wn * SEQ + k) * SEQ + q];  // mask symmetric in !=0
            if (mk == 0.0f) {
                int kd = k / 49, kh = (k / 7) % 7, kw = k % 7;
                int rel = (qd - kd + 6) * 169 + (qh - kh + 6) * 13 + (qw - kw + 6);
                val = rpb[(size_t)rel * NHEAD + h] * LOG2E;
            }
        }
        v[t] = __half_as_ushort(__float2half_rn(val));
    }
    uint2 pk = {v[0] | (v[1] << 16), v[2] | (v[3] << 16)};
    cb4[((size_t)(cl * NHEAD + h) * 88 + k4) * 352 + q] = pk;
}

// ---------------- 32x32x16 MFMA GEMM, global_load_lds staging, swizzled LDS (linear dest,
// pre-swizzled global source; read applies same XOR). BM=128, BK=64 (rows = 128B exactly).
// MODE 0 (qkv): BN=192, grid.x in {0,1,2} -> Q(scaled)/K -> outH[row][384]; V -> outV transposed.
// MODE 1: BN=64, outF[row*N+col] += acc + bias  (residual fp32)
// MODE 2 (GLU): BN=64, Wt rows [n0,n0+64)=u, [768+n0,...)=g; outB = bf16(u * gelu(g))
template <int MODE>
__global__ __launch_bounds__(256) void k_gemm32(const unsigned short* __restrict__ A,
                                                const unsigned short* __restrict__ Wt,
                                                const float* __restrict__ bias,
                                                float* __restrict__ outF,
                                                unsigned short* __restrict__ outB,
                                                _Float16* __restrict__ outH,
                                                _Float16* __restrict__ outV,
                                                int N, int K) {
    constexpr int BN = (MODE == 0) ? 192 : 64;
    constexpr int NF = (MODE == 0) ? 3 : 1;          // n-frags (of 32) per wave
    constexpr int WNC = NF * 32;                     // wave n-extent
    constexpr int BROWS = (MODE == 0) ? 192 : ((MODE == 2) ? 128 : 64);
    constexpr int BCH = (BROWS * 128) / 4096;        // B DMA chunks
    __shared__ char AsB[16384];
    __shared__ char BsB[BROWS * 128];
    const int tid = threadIdx.x;
    const int n0 = blockIdx.x * BN;
    const size_t m0 = (size_t)blockIdx.y * 128;
    const int lane = tid & 63, wid = tid >> 6;
    const int wm = wid >> 1, wn = wid & 1;
    const int ln31 = lane & 31, hi16 = (lane >> 5) * 16;
    const int xorv = (ln31 & 7) << 4;
    const size_t ldb = (size_t)K * 2;  // row pitch (bytes) of both A and Wt

    f32x16 acc[2][NF];
    f32x16 accG[2];
#pragma unroll
    for (int mi = 0; mi < 2; ++mi) {
#pragma unroll
        for (int nj = 0; nj < NF; ++nj) acc[mi][nj] = (f32x16)(0.f);
        accG[mi] = (f32x16)(0.f);
    }

    for (int kb = 0; kb < K; kb += 64) {
        // ---- stage A (16 KB) + B via DMA, global source pre-swizzled
#pragma unroll
        for (int i = 0; i < 4; ++i) {
            int s = i * 4096 + tid * 16;
            int r = s >> 7;
            int cb = (s & 127) ^ ((r & 7) << 4);
            gld16(AsB + s, (const char*)A + (m0 + r) * ldb + (size_t)kb * 2 + cb);
        }
#pragma unroll
        for (int i = 0; i < BCH; ++i) {
            int s = i * 4096 + tid * 16;
            int r = s >> 7;
            int cb = (s & 127) ^ ((r & 7) << 4);
            int grow = n0 + r + ((MODE == 2 && r >= 64) ? 704 : 0);
            gld16(BsB + s, (const char*)Wt + (size_t)grow * ldb + (size_t)kb * 2 + cb);
        }
        __syncthreads();
        // ---- compute 4 k-steps of 16
#pragma unroll
        for (int ks = 0; ks < 4; ++ks) {
            const int ccb = (ks * 32 + hi16) ^ xorv;
            bf16x8 a0 = *(const bf16x8*)(AsB + (wm * 64 + ln31) * 128 + ccb);
            bf16x8 a1 = *(const bf16x8*)(AsB + (wm * 64 + 32 + ln31) * 128 + ccb);
            if (MODE == 2) {
                bf16x8 bu = *(const bf16x8*)(BsB + (wn * 32 + ln31) * 128 + ccb);
                bf16x8 bg = *(const bf16x8*)(BsB + (64 + wn * 32 + ln31) * 128 + ccb);
                acc[0][0] = __builtin_amdgcn_mfma_f32_32x32x16_bf16(a0, bu, acc[0][0], 0, 0, 0);
                acc[1][0] = __builtin_amdgcn_mfma_f32_32x32x16_bf16(a1, bu, acc[1][0], 0, 0, 0);
                accG[0] = __builtin_amdgcn_mfma_f32_32x32x16_bf16(a0, bg, accG[0], 0, 0, 0);
                accG[1] = __builtin_amdgcn_mfma_f32_32x32x16_bf16(a1, bg, accG[1], 0, 0, 0);
            } else {
#pragma unroll
                for (int nj = 0; nj < NF; ++nj) {
                    bf16x8 b = *(const bf16x8*)(BsB + (wn * WNC + nj * 32 + ln31) * 128 + ccb);
                    acc[0][nj] = __builtin_amdgcn_mfma_f32_32x32x16_bf16(a0, b, acc[0][nj], 0, 0, 0);
                    acc[1][nj] = __builtin_amdgcn_mfma_f32_32x32x16_bf16(a1, b, acc[1][nj], 0, 0, 0);
                }
            }
        }
        __syncthreads();
    }

    // ---- epilogue. C/D: col=lane&31, row=(reg&3)+8*(reg>>2)+4*(lane>>5)
    const float S2LOG = 0.17677669529663687f * 1.4426950408889634f;  // scale*log2e
    const int rbase = (int)m0 + wm * 64 + ((lane >> 5) << 2);
    const int cbase = n0 + wn * WNC + ln31;
#pragma unroll
    for (int mi = 0; mi < 2; ++mi) {
#pragma unroll
        for (int nj = 0; nj < NF; ++nj) {
            const int gc = cbase + nj * 32;
            const float bb = bias[gc];
            const float bgv = (MODE == 2) ? bias[768 + gc] : 0.f;
#pragma unroll
            for (int reg = 0; reg < 16; ++reg) {
                const int row = rbase + mi * 32 + (reg & 3) + ((reg >> 2) << 3);
                float v = acc[mi][nj][reg] + bb;
                if (MODE == 1) {
                    outF[(size_t)row * N + gc] += v;
                } else if (MODE == 0) {
                    if (n0 < 384) {
                        outH[(size_t)row * 384 + gc] = (_Float16)(n0 == 0 ? v * S2LOG : v);
                    } else {
                        int d = gc - 384, hh = d >> 5, dd = d & 31;
                        int wnn = row / 343, qq = row - wnn * 343;
                        outV[(((size_t)wnn * NHEAD + hh) * 32 + dd) * 344 + qq] = (_Float16)v;
                    }
                } else {
                    float g = accG[mi][reg] + bgv;
                    outB[(size_t)row * 768 + gc] = f2bf(v * gelu_tanh(g));
                }
            }
        }
    }
}

// ---------------- attn5: attn3 flow + correct row&3 chunk swizzle + packed-f16 bias/max +
// tiny per-wave Pb (b64 write / b128 read, same-wave in-order DS). 48KB LDS -> 3 blocks/CU.
__global__ __launch_bounds__(256) void k_attn5(const _Float16* __restrict__ qk,  // [TOK][384]
                                               const _Float16* __restrict__ vt,  // [128][6][32][344]
                                               const uint2* __restrict__ cb4,
                                               unsigned short* __restrict__ o) {
    __shared__ _Float16 Ks[352 * 32];      // 22528 B, chunk' = chunk ^ (row&3)
    __shared__ _Float16 Vt[32 * 352];      // 22528 B, chunk' = chunk ^ (d&3)
    __shared__ _Float16 Pb[4 * 16 * 32];   // 4096 B: [wid][qloc][slot^(qloc&6)][4]
    const int h = blockIdx.x;
    const int wn = blockIdx.y;
    const int tid = threadIdx.x;
    // stage K (352 rows x 4 chunks of 16B; rows>=343 zero)
    const _Float16* kbase = qk + (size_t)wn * SEQ * 384 + 192 + h * 32;
    for (int j = tid; j < 1408; j += 256) {
        int s = j >> 2, c = j & 3;
        int slot = c ^ (s & 3);
        half8 v = {};
        if (s < SEQ) v = *(const half8*)&kbase[(size_t)s * 384 + c * 8];
        *(half8*)&Ks[s * 32 + slot * 8] = v;
    }
    // stage V^T (32 d x 44 chunks; k>=343 zero)
    const _Float16* vbase = vt + ((size_t)wn * NHEAD + h) * 32 * 344;
    for (int j = tid; j < 1408; j += 256) {
        int d = j / 44, c = j % 44;
        int slot = c ^ (d & 3);
        int cb8 = c * 8;
        half8 v = {};
        if (cb8 + 7 <= 342) {
            v = *(const half8*)&vbase[(size_t)d * 344 + cb8];
        } else if (cb8 <= 342) {
#pragma unroll
            for (int i = 0; i < 8; ++i) v[i] = (cb8 + i <= 342) ? vbase[(size_t)d * 344 + cb8 + i] : (_Float16)0.f;
        }
        *(half8*)&Vt[d * 352 + slot * 8] = v;
    }
    __syncthreads();
    const int wid = tid >> 6, lane = tid & 63;
    const int qloc = lane & 15, g = lane >> 4;
    const int x3 = qloc & 3;
    const int x6 = qloc & 6;
    const int slotK = (g ^ x3) * 8;
    const int pb = (wid * 16 + qloc) * 32;  // half index of this lane's Pb row
    int cls = (((wn >> 5) == 3) ? 4 : 0) | ((((wn >> 2) & 7) == 7) ? 2 : 0) | (((wn & 3) == 3) ? 1 : 0);
    const uint2* cbb = cb4 + (size_t)(cls * NHEAD + h) * 88 * 352;
    for (int qt = wid; qt < 22; qt += 4) {
        const int q0 = qt * 16;
        const int qrow = q0 + qloc;
        half8 qf = {};
        if (qrow < SEQ) qf = *(const half8*)&qk[((size_t)wn * SEQ + qrow) * 384 + h * 32 + g * 8];
        unsigned spk[22][2];
        hv2 mpk = {(_Float16)(-60000.0f), (_Float16)(-60000.0f)};
        __builtin_amdgcn_s_setprio(1);
#pragma unroll
        for (int kt = 0; kt < 22; ++kt) {
            half8 kf = *(const half8*)&Ks[(kt * 16 + qloc) * 32 + slotK];
            f32x4 st = __builtin_amdgcn_mfma_f32_16x16x32_f16(kf, qf, (f32x4){0.f, 0.f, 0.f, 0.f}, 0, 0, 0);
            uint2 cv = cbb[(size_t)(kt * 4 + g) * 352 + qrow];
            hv2 s01 = pkrtz(st[0], st[1]) + u2h2(cv.x);
            hv2 s23 = pkrtz(st[2], st[3]) + u2h2(cv.y);
            mpk = __builtin_elementwise_max(mpk, __builtin_elementwise_max(s01, s23));
            spk[kt][0] = h22u(s01);
            spk[kt][1] = h22u(s23);
        }
        __builtin_amdgcn_s_setprio(0);
        float mf = fmaxf((float)mpk[0], (float)mpk[1]);
        mf = fmaxf(mf, __shfl_xor(mf, 16));
        mf = fmaxf(mf, __shfl_xor(mf, 32));
        float l = 0.f;
        f32x4 acc0 = {0.f, 0.f, 0.f, 0.f}, acc1 = {0.f, 0.f, 0.f, 0.f};
        // per 32-k chunk: exp(2 kt) -> Pb write -> b128 read (B-frag) -> 2 PV MFMA.
        // Same-wave DS in-order pipe makes write->read safe without explicit waits.
#pragma unroll
        for (int ch = 0; ch < 11; ++ch) {
            hv2 a0 = u2h2(spk[2 * ch][0]), a1 = u2h2(spk[2 * ch][1]);
            hv2 b0 = u2h2(spk[2 * ch + 1][0]), b1 = u2h2(spk[2 * ch + 1][1]);
            float e0 = exp2f((float)a0[0] - mf), e1 = exp2f((float)a0[1] - mf);
            float e2 = exp2f((float)a1[0] - mf), e3 = exp2f((float)a1[1] - mf);
            float e4 = exp2f((float)b0[0] - mf), e5 = exp2f((float)b0[1] - mf);
            float e6 = exp2f((float)b1[0] - mf), e7 = exp2f((float)b1[1] - mf);
            l += ((e0 + e1) + (e2 + e3)) + ((e4 + e5) + (e6 + e7));
            uint2 wlo = {h22u(pkrtz(e0, e1)), h22u(pkrtz(e2, e3))};
            uint2 whi = {h22u(pkrtz(e4, e5)), h22u(pkrtz(e6, e7))};
            *(uint2*)&Pb[pb + ((g ^ x6) << 2)] = wlo;        // k = 32ch + 4g + 0..3
            *(uint2*)&Pb[pb + (((4 + g) ^ x6) << 2)] = whi;  // k = 32ch + 16 + 4g + 0..3
            half8 pf = *(const half8*)&Pb[pb + (((2 * g) ^ x6) << 2)];  // k = 32ch + 8g + 0..7
            const int slotV = ((ch * 4 + g) ^ x3) * 8;
            half8 v0 = *(const half8*)&Vt[qloc * 352 + slotV];
            half8 v1 = *(const half8*)&Vt[(qloc + 16) * 352 + slotV];
            acc0 = __builtin_amdgcn_mfma_f32_16x16x32_f16(v0, pf, acc0, 0, 0, 0);
            acc1 = __builtin_amdgcn_mfma_f32_16x16x32_f16(v1, pf, acc1, 0, 0, 0);
        }
        l += __shfl_xor(l, 16);
        l += __shfl_xor(l, 32);
        if (qrow < SEQ) {
            float inv = 1.0f / l;
            unsigned short* orow = o + ((size_t)wn * SEQ + qrow) * CCH + h * 32;
            ushort4 w0 = {f2bf(acc0[0] * inv), f2bf(acc0[1] * inv),
                          f2bf(acc0[2] * inv), f2bf(acc0[3] * inv)};
            ushort4 w1 = {f2bf(acc1[0] * inv), f2bf(acc1[1] * inv),
                          f2bf(acc1[2] * inv), f2bf(acc1[3] * inv)};
            *(ushort4*)&orow[g * 4] = w0;
            *(ushort4*)&orow[16 + g * 4] = w1;
        }
    }
}

extern "C" void kernel_launch(void* const* d_in, const int* in_sizes, int n_in,
                              void* d_out, int out_size, void* d_ws, size_t ws_size,
                              hipStream_t stream) {
    const float* x     = (const float*)d_in[0];
    const float* mask  = (const float*)d_in[1];
    const float* ln1_w = (const float*)d_in[3];
    const float* ln1_b = (const float*)d_in[4];
    const float* qkv_w = (const float*)d_in[5];
    const float* qkv_b = (const float*)d_in[6];
    const float* out_w = (const float*)d_in[7];
    const float* out_b = (const float*)d_in[8];
    const float* ln2_w = (const float*)d_in[9];
    const float* ln2_b = (const float*)d_in[10];
    const float* ff1_w = (const float*)d_in[11];
    const float* ff1_b = (const float*)d_in[12];
    const float* ff2_w = (const float*)d_in[13];
    const float* ff2_b = (const float*)d_in[14];
    const float* rpb   = (const float*)d_in[15];
    const float* lnf_w = (const float*)d_in[16];
    const float* lnf_b = (const float*)d_in[17];

    char* wsp = (char*)d_ws;
    float* xw = (float*)wsp;                          wsp += (size_t)TOK * 192 * 4;
    unsigned short* hdnb = (unsigned short*)wsp;      wsp += (size_t)TOK * 192 * 2;
    _Float16* qkh = (_Float16*)wsp;                   wsp += (size_t)TOK * 384 * 2;
    _Float16* vth = (_Float16*)wsp;                   wsp += (size_t)NWIN * NHEAD * 32 * 344 * 2;
    unsigned short* glub = (unsigned short*)wsp;      wsp += (size_t)TOK * 768 * 2;
    unsigned short* wt = (unsigned short*)wsp;        wsp += (size_t)1179648 * 2;
    uint2* cb4 = (uint2*)wsp;                         // 48*88*352*8 = 11.9 MB
    float* out = (float*)d_out;

    k_shift_part<<<8232, 256, 0, stream>>>(x, xw);
    k_wprep<<<4608, 256, 0, stream>>>(qkv_w, out_w, ff1_w, ff2_w, wt);
    for (int l = 0; l < 2; ++l) {
        unsigned short* wbase = wt + (size_t)l * 589824;
        k_cbgen3<<<dim3(88, NHEAD, 8), 352, 0, stream>>>(mask, rpb + (size_t)l * 2197 * NHEAD, cb4);
        k_ln_bf<<<10976, 256, 0, stream>>>(xw, ln1_w + l * 192, ln1_b + l * 192, hdnb, TOK);
        k_gemm32<0><<<dim3(3, 343), 256, 0, stream>>>(hdnb, wbase, qkv_b + l * 576,
                                                      nullptr, nullptr, qkh, vth, 576, 192);
        k_attn5<<<dim3(NHEAD, NWIN), 256, 0, stream>>>(qkh, vth, cb4, hdnb);
        k_gemm32<1><<<dim3(3, 343), 256, 0, stream>>>(hdnb, wbase + 110592, out_b + l * 192,
                                                      xw, nullptr, nullptr, nullptr, 192, 192);
        k_ln_bf<<<10976, 256, 0, stream>>>(xw, ln2_w + l * 192, ln2_b + l * 192, hdnb, TOK);
        k_gemm32<2><<<dim3(12, 343), 256, 0, stream>>>(hdnb, wbase + 147456, ff1_b + l * 1536,
                                                       nullptr, glub, nullptr, nullptr, 768, 192);
        k_gemm32<1><<<dim3(3, 343), 256, 0, stream>>>(glub, wbase + 442368, ff2_b + l * 192,
                                                      xw, nullptr, nullptr, nullptr, 192, 768);
    }
    k_ln_out<<<10976, 256, 0, stream>>>(xw, lnf_w, lnf_b, out);
}